// Round 9
// baseline (585.498 us; speedup 1.0000x reference)
//
#include <hip/hip_runtime.h>
#include <hip/hip_bf16.h>
#include <math.h>

// ---------------------------------------------------------------------------
// YatNMN: out = scale * ( y^2/(||x||^2+||w||^2-2y+eps) + bias ), y = x@W
// x:[16384,2048] f32, W:[2048,8192] f32, out f32 [16384,8192].
// R9 = R8 with the nontemporal builtin type fix (clang ext_vector_type
// pointers, not HIP_vector_type): NT stores for the 512MB output stream,
// NT loads for read-once fp32 inputs in the prologues.
// Workspace: [0) xbf 64MB | [64M) ktb 32MB | xs | ks | kpart (<=2MB)
// ---------------------------------------------------------------------------

#define EPS_F (1.0f / 137.0f)
#define M_DIM 16384
#define N_DIM 8192
#define K_DIM 2048

typedef __attribute__((ext_vector_type(8))) short short8;
typedef __attribute__((ext_vector_type(4))) float f32x4;

__device__ __forceinline__ unsigned short f2bf(float f) {
  unsigned int u = __float_as_uint(f);
  u += 0x7fffu + ((u >> 16) & 1u);
  return (unsigned short)(u >> 16);
}

typedef __attribute__((address_space(1))) const unsigned int as1_cuint;
typedef __attribute__((address_space(3))) unsigned int as3_uint;

__device__ __forceinline__ void gload16(const void* g, void* lds_wave_base) {
  __builtin_amdgcn_global_load_lds((as1_cuint*)g, (as3_uint*)lds_wave_base, 16, 0, 0);
}

// --------------------------- prologue kernels ------------------------------

__global__ __launch_bounds__(256) void k_conv_x(const float* __restrict__ x,
                                                unsigned short* __restrict__ xbf,
                                                float* __restrict__ xs) {
  const int row = blockIdx.x;
  const int t = threadIdx.x;
  const f32x4* xr = (const f32x4*)(x + (size_t)row * K_DIM);
  ushort4* orow = (ushort4*)(xbf + (size_t)row * K_DIM);
  float s = 0.f;
#pragma unroll
  for (int i = 0; i < 2; ++i) {
    f32x4 v = __builtin_nontemporal_load(&xr[t + i * 256]);  // read-once
    s += v.x * v.x + v.y * v.y + v.z * v.z + v.w * v.w;
    ushort4 o;
    o.x = f2bf(v.x); o.y = f2bf(v.y); o.z = f2bf(v.z); o.w = f2bf(v.w);
    orow[t + i * 256] = o;  // cached: GEMM reads this soon
  }
#pragma unroll
  for (int off = 32; off > 0; off >>= 1) s += __shfl_down(s, off, 64);
  __shared__ float red[4];
  if ((t & 63) == 0) red[t >> 6] = s;
  __syncthreads();
  if (t == 0) xs[row] = red[0] + red[1] + red[2] + red[3];
}

// W [K][N] f32 -> W^T [N][K] bf16, fused per-(32-row-block, col) ssq partials.
__global__ __launch_bounds__(256) void k_conv_kT_fused(const float* __restrict__ w,
                                                       unsigned short* __restrict__ bt,
                                                       float* __restrict__ kpart) {
  __shared__ float tile[32][33];
  __shared__ float psum[8][33];
  const int tx = threadIdx.x;
  const int ty = threadIdx.y;
  const int n0 = blockIdx.x * 32;
  const int k0 = blockIdx.y * 32;
  float ss = 0.f;
#pragma unroll
  for (int j = 0; j < 32; j += 8) {
    float v = __builtin_nontemporal_load(&w[(size_t)(k0 + ty + j) * N_DIM + n0 + tx]);
    tile[ty + j][tx] = v;
    ss += v * v;
  }
  psum[ty][tx] = ss;
  __syncthreads();
#pragma unroll
  for (int j = 0; j < 32; j += 8)
    bt[(size_t)(n0 + ty + j) * K_DIM + k0 + tx] = f2bf(tile[tx][ty + j]);
  if (ty == 0) {
    float s = 0.f;
#pragma unroll
    for (int r = 0; r < 8; ++r) s += psum[r][tx];
    kpart[(size_t)(k0 >> 5) * N_DIM + n0 + tx] = s;
  }
}

__global__ __launch_bounds__(256) void k_conv_kT(const float* __restrict__ w,
                                                 unsigned short* __restrict__ bt) {
  __shared__ float tile[32][33];
  const int tx = threadIdx.x;
  const int ty = threadIdx.y;
  const int n0 = blockIdx.x * 32;
  const int k0 = blockIdx.y * 32;
#pragma unroll
  for (int j = 0; j < 32; j += 8)
    tile[ty + j][tx] = __builtin_nontemporal_load(&w[(size_t)(k0 + ty + j) * N_DIM + n0 + tx]);
  __syncthreads();
#pragma unroll
  for (int j = 0; j < 32; j += 8)
    bt[(size_t)(n0 + ty + j) * K_DIM + k0 + tx] = f2bf(tile[tx][ty + j]);
}

__global__ __launch_bounds__(256) void k_ksq_part(const float* __restrict__ w,
                                                  float* __restrict__ kpart) {
  const int col = blockIdx.x * 256 + threadIdx.x;
  const int kb = blockIdx.y;
  float s = 0.f;
#pragma unroll 4
  for (int k = kb * 128; k < kb * 128 + 128; ++k) {
    float v = w[(size_t)k * N_DIM + col];
    s += v * v;
  }
  kpart[kb * N_DIM + col] = s;
}

__global__ __launch_bounds__(256) void k_ksq_fin(const float* __restrict__ kpart,
                                                 float* __restrict__ ks, int nkb) {
  const int col = blockIdx.x * 256 + threadIdx.x;
  float s = 0.f;
  for (int kb = 0; kb < nkb; ++kb) s += kpart[(size_t)kb * N_DIM + col];
  ks[col] = s;
}

// ------------------------------- GEMM 256x256 ------------------------------
// Structure identical to R7 (see R7 comments). Only change: epilogue uses
// __builtin_nontemporal_store for the 512MB write-once output stream.

#define MFMA_OP(d, va, vb) \
  d = __builtin_amdgcn_mfma_f32_16x16x32_bf16(va, vb, d, 0, 0, 0)

#define BARRIER __builtin_amdgcn_s_barrier()
#define LGKM0_SGB do { \
  asm volatile("s_waitcnt lgkmcnt(0)" ::: "memory"); \
  __builtin_amdgcn_sched_barrier(0); \
} while (0)
#define VMCNT6 asm volatile("s_waitcnt vmcnt(6)" ::: "memory")

__global__ __launch_bounds__(512) void k_gemm(const unsigned short* __restrict__ A,
                                              const unsigned short* __restrict__ B,
                                              const float* __restrict__ xs,
                                              const float* __restrict__ ks,
                                              const float* __restrict__ bias,
                                              const float* __restrict__ alpha,
                                              float* __restrict__ out) {
  __shared__ __align__(16) char lds[131072];
  char* sA = lds;
  char* sB = lds + 65536;

  const int t = threadIdx.x;
  const int lane = t & 63;
  const int wid = t >> 6;
  const int wr = wid >> 2;  // 0..1 (M)
  const int wc = wid & 3;   // 0..3 (N)
  const int lr = lane & 15;
  const int kh = lane >> 4;
  const int swz = (lr & 7) << 4;

  // 2D-chunked XCD swizzle (bijective: 2048 = 8 xcd * 8 chunks * 32).
  const int bid = blockIdx.x;
  const int xcd = bid & 7;
  const int sub = bid >> 3;
  const int c   = sub >> 5;
  const int tm = ((xcd >> 1) << 4) + ((c >> 1) << 2) + ((sub >> 3) & 3);
  const int tn = ((xcd & 1) << 4) + ((c & 1) << 3) + (sub & 7);
  const size_t rowM0 = (size_t)tm * 256;
  const size_t colN0 = (size_t)tn * 256;

  const int l8 = lane >> 3;
  const int col16 = (lane & 7) ^ (l8 & 7);  // inverse-swizzled 16B slot
  const int rA_base = (wid < 4) ? wid * 8 : 128 + (wid - 4) * 8;
  const unsigned short* gA0 = A + (rowM0 + rA_base + l8) * K_DIM + col16 * 8;
  const unsigned short* gB0 = B + (colN0 + wid * 8 + l8) * K_DIM + col16 * 8;

#define STAGE_A(b, s, ko) \
  gload16(gA0 + (size_t)(s) * 32 * K_DIM + (ko), \
          sA + (b) * 32768 + (rA_base + (s) * 32) * 128)
#define STAGE_B(b, j, ko) \
  gload16(gB0 + (size_t)(j) * 64 * K_DIM + (ko), \
          sB + (b) * 32768 + ((j) * 64 + wid * 8) * 128)

#define RD_A(b, m, kk) \
  (*(const short8*)(sA + (b) * 32768 + (wr * 128 + (m) * 16 + lr) * 128 + \
                    (((kk) * 64 + kh * 16) ^ swz)))
#define RD_B(b, n, kk) \
  (*(const short8*)(sB + (b) * 32768 + (wc * 64 + (n) * 16 + lr) * 128 + \
                    (((kk) * 64 + kh * 16) ^ swz)))

  f32x4 acc[8][4] = {};
  short8 a0, a1, a2, a3;  // current pair: m_lo kk0/kk1, m_hi kk0/kk1
  short8 b[8];            // b[n]=kk0, b[4+n]=kk1

#define LOAD_A4(bf, mb) do { \
  a0 = RD_A(bf, mb, 0); a1 = RD_A(bf, mb, 1); \
  a2 = RD_A(bf, (mb)+1, 0); a3 = RD_A(bf, (mb)+1, 1); \
} while (0)
#define LOAD_B8(bf) do { \
  b[0] = RD_B(bf, 0, 0); b[1] = RD_B(bf, 1, 0); b[2] = RD_B(bf, 2, 0); b[3] = RD_B(bf, 3, 0); \
  b[4] = RD_B(bf, 0, 1); b[5] = RD_B(bf, 1, 1); b[6] = RD_B(bf, 2, 1); b[7] = RD_B(bf, 3, 1); \
} while (0)

#define MFMA16(mb) do { \
  __builtin_amdgcn_s_setprio(1); \
  MFMA_OP(acc[mb][0], a0, b[0]); MFMA_OP(acc[mb][1], a0, b[1]); \
  MFMA_OP(acc[mb][2], a0, b[2]); MFMA_OP(acc[mb][3], a0, b[3]); \
  MFMA_OP(acc[(mb)+1][0], a2, b[0]); MFMA_OP(acc[(mb)+1][1], a2, b[1]); \
  MFMA_OP(acc[(mb)+1][2], a2, b[2]); MFMA_OP(acc[(mb)+1][3], a2, b[3]); \
  MFMA_OP(acc[mb][0], a1, b[4]); MFMA_OP(acc[mb][1], a1, b[5]); \
  MFMA_OP(acc[mb][2], a1, b[6]); MFMA_OP(acc[mb][3], a1, b[7]); \
  MFMA_OP(acc[(mb)+1][0], a3, b[4]); MFMA_OP(acc[(mb)+1][1], a3, b[5]); \
  MFMA_OP(acc[(mb)+1][2], a3, b[6]); MFMA_OP(acc[(mb)+1][3], a3, b[7]); \
  __builtin_amdgcn_s_setprio(0); \
} while (0)

#define TILE(bf, RF, S1, S2, S3) do { \
  RF; \
  LOAD_B8(bf); LOAD_A4(bf, 0); \
  BARRIER; LGKM0_SGB; MFMA16(0); BARRIER; \
  LOAD_A4(bf, 2); S1; \
  BARRIER; LGKM0_SGB; MFMA16(2); BARRIER; \
  LOAD_A4(bf, 4); S2; \
  BARRIER; LGKM0_SGB; MFMA16(4); BARRIER; \
  LOAD_A4(bf, 6); S3; \
  BARRIER; LGKM0_SGB; MFMA16(6); VMCNT6; BARRIER; \
} while (0)

  // prologue: T0 full (8 calls) -> buf0; T1 stripes 0-2 + B0-2 (6) -> buf1
  STAGE_A(0, 0, 0); STAGE_B(0, 0, 0);
  STAGE_A(0, 1, 0); STAGE_B(0, 1, 0);
  STAGE_A(0, 2, 0); STAGE_B(0, 2, 0);
  STAGE_A(0, 3, 0); STAGE_B(0, 3, 0);
  STAGE_A(1, 0, 64); STAGE_B(1, 0, 64);
  STAGE_A(1, 1, 64); STAGE_B(1, 1, 64);
  STAGE_A(1, 2, 64); STAGE_B(1, 2, 64);
  VMCNT6;  // T0's 8 landed; T1's 6 in flight
  BARRIER;

#pragma unroll 1
  for (int it = 0; it < 16; ++it) {
    const int kT1 = it * 128 + 64;                    // tile 2it+1 (real)
    const int kS0 = (it < 15) ? it * 128 + 128 : 0;   // tile 2it+2 (clamped)
    const int kS1 = (it < 15) ? it * 128 + 192 : 0;   // tile 2it+3 (clamped)
    // even tile 2it (buf0): finish T1, stage T2 -> buf0
    TILE(0,
         (STAGE_A(1, 3, kT1), STAGE_B(1, 3, kT1)),
         (STAGE_A(0, 0, kS0), STAGE_B(0, 0, kS0)),
         (STAGE_A(0, 1, kS0), STAGE_B(0, 1, kS0)),
         (STAGE_A(0, 2, kS0), STAGE_B(0, 2, kS0)));
    // odd tile 2it+1 (buf1): finish T2, stage T3 -> buf1
    TILE(1,
         (STAGE_A(0, 3, kS0), STAGE_B(0, 3, kS0)),
         (STAGE_A(1, 0, kS1), STAGE_B(1, 0, kS1)),
         (STAGE_A(1, 1, kS1), STAGE_B(1, 1, kS1)),
         (STAGE_A(1, 2, kS1), STAGE_B(1, 2, kS1)));
  }

  asm volatile("s_waitcnt vmcnt(0)" ::: "memory");

  // fused Yat epilogue. C/D: col = lane&15 (N), row = (lane>>4)*4 + reg (M).
  // Output is write-once: non-temporal stores keep A/B panels in L2/L3.
  const float scale = powf(sqrtf(8192.0f) / log1pf(8192.0f), alpha[0]);
#pragma unroll
  for (int m = 0; m < 8; ++m) {
#pragma unroll
    for (int r = 0; r < 4; ++r) {
      const size_t grow = rowM0 + wr * 128 + m * 16 + kh * 4 + r;
      const float xq = xs[grow];
      float* orow = out + grow * N_DIM;
#pragma unroll
      for (int n = 0; n < 4; ++n) {
        const int gcol = (int)colN0 + wc * 64 + n * 16 + lr;
        const float y = acc[m][n][r];
        const float d = xq + ks[gcol] - 2.0f * y + EPS_F;
        const float v = y * y * __builtin_amdgcn_rcpf(d);
        __builtin_nontemporal_store((v + bias[gcol]) * scale, &orow[gcol]);
      }
    }
  }
}

// ------------------------------ launch -------------------------------------

extern "C" void kernel_launch(void* const* d_in, const int* in_sizes, int n_in,
                              void* d_out, int out_size, void* d_ws, size_t ws_size,
                              hipStream_t stream) {
  const float* x     = (const float*)d_in[0];
  const float* w     = (const float*)d_in[1];
  const float* bias  = (const float*)d_in[2];
  const float* alpha = (const float*)d_in[3];
  float* out = (float*)d_out;
  char* ws = (char*)d_ws;

  unsigned short* xbf = (unsigned short*)(ws);
  unsigned short* ktb = (unsigned short*)(ws + 67108864);
  float* xs    = (float*)(ws + 100663296);
  float* ks    = (float*)(ws + 100728832);
  float* kpart = (float*)(ws + 100761600);

  k_conv_x<<<M_DIM, 256, 0, stream>>>(x, xbf, xs);
  if (ws_size >= 100761600ull + (size_t)64 * N_DIM * 4) {
    k_conv_kT_fused<<<dim3(N_DIM / 32, K_DIM / 32), dim3(32, 8), 0, stream>>>(w, ktb, kpart);
    k_ksq_fin<<<N_DIM / 256, 256, 0, stream>>>(kpart, ks, 64);
  } else {
    k_conv_kT<<<dim3(N_DIM / 32, K_DIM / 32), dim3(32, 8), 0, stream>>>(w, ktb);
    k_ksq_part<<<dim3(N_DIM / 256, 16), 256, 0, stream>>>(w, kpart);
    k_ksq_fin<<<N_DIM / 256, 256, 0, stream>>>(kpart, ks, 16);
  }
  k_gemm<<<(M_DIM / 256) * (N_DIM / 256), 512, 0, stream>>>(xbf, ktb, xs, ks, bias, alpha, out);
}